// Round 9
// baseline (2162.700 us; speedup 1.0000x reference)
//
#include <hip/hip_runtime.h>
#include <math.h>

// dims (hardcoded per reference)
#define T_STEPS 50
#define BB 8   // batch rows per block; grid = 2048/8 = 256 blocks = 1 per CU

// LDS pool offsets (floats)
#define O_XH    0        // xh_T[64][8]   (k-major, row minor; b128 broadcast reads)
#define O_HT    512      // h_T[6][64][8]
#define O_HNT   3584     // hn_T[6][64][8]
#define O_QC    6656     // qc_R[6][8][128]
#define O_KC    12800    // kc_R[6][8][128]
#define O_VC    18944    // vc_R[6][8][64]
#define O_LG    22016    // logits [8][6]
#define POOL_F  22080    // 88,320 B LDS

__device__ __forceinline__ void fma4(float4& a, const float4 v, const float s) {
  a.x = fmaf(v.x, s, a.x); a.y = fmaf(v.y, s, a.y);
  a.z = fmaf(v.z, s, a.z); a.w = fmaf(v.w, s, a.w);
}
__device__ __forceinline__ float sigmoidf_(float x) { return 1.0f / (1.0f + __expf(-x)); }
__device__ __forceinline__ float tanhf_(float x) {
  float ax = fabsf(x);
  float e = __expf(-2.0f * ax);
  float t = (1.0f - e) / (1.0f + e);
  return copysignf(t, x);
}

// Wcomb[r][k][g] = sum_v Wv[k][v] * Wih[r][v][g]  : [6][64][192] f32
__global__ void wcomb_kernel(const float* __restrict__ Wv, const float* __restrict__ Wih,
                             float* __restrict__ Wc) {
  int g = threadIdx.x;          // 0..191
  int f = blockIdx.x & 63;      // 0..63
  int r = blockIdx.x >> 6;      // 0..5
  float acc = 0.f;
#pragma unroll 8
  for (int v = 0; v < 128; ++v)
    acc = fmaf(Wv[f * 128 + v], Wih[(r * 128 + v) * 192 + g], acc);
  Wc[(r * 64 + f) * 192 + g] = acc;
}

// waves_per_eu(4,4): 128-VGPR budget for the 16-wave block (R6: default=64 -> spill).
__global__ __launch_bounds__(1024, 1) __attribute__((amdgpu_waves_per_eu(4, 4)))
void rims_kernel(
    const float* __restrict__ x, const float* __restrict__ statics,
    const float* __restrict__ maskp, const float* __restrict__ delta,
    const float* __restrict__ xlast, const float* __restrict__ xmean,
    const float* __restrict__ wdgp, const float* __restrict__ bdgp,
    const float* __restrict__ Wk, const float* __restrict__ Wq,
    const float* __restrict__ Whh, const float* __restrict__ bih,
    const float* __restrict__ bhh, const float* __restrict__ Wqc,
    const float* __restrict__ Wkc, const float* __restrict__ Wvc,
    const float* __restrict__ W1, const float* __restrict__ b1,
    const float* __restrict__ W2, const float* __restrict__ b2,
    const float* __restrict__ Wcomb, float* __restrict__ out) {
  __shared__ float pool[POOL_F];

  const int tid = threadIdx.x;
  const int wave = tid >> 6;   // 0..15
  const int lane = tid & 63;
  const int b0 = blockIdx.x * BB;

  for (int i = tid; i < 3072; i += 1024) pool[O_HT + i] = 0.f;

  // X-phase constants (waves 0..7 own X-row = wave)
  const float wdg = wdgp[lane];
  const float bdg = bdgp[lane];
  const float xmv = xmean[(size_t)(b0 + (wave & 7)) * 64 + lane];
  // G1 biases (waves 0..11 own rim r = wave>>1); r/z biases pre-combined
  float bR = 0.f, bZ = 0.f, bin = 0.f, bhn = 0.f;
  if (wave < 12) {
    const int r = wave >> 1;
    bR = bih[r * 192 + lane] + bhh[r * 192 + lane];
    bZ = bih[r * 192 + 64 + lane] + bhh[r * 192 + 64 + lane];
    bin = bih[r * 192 + 128 + lane];
    bhn = bhh[r * 192 + 128 + lane];
  }
  // X for t=0
  if (wave < 8) {
    size_t off = ((size_t)(b0 + wave) * T_STEPS + 0) * 64 + lane;
    float xt = x[off], mt = maskp[off], dt = delta[off], xl = xlast[off];
    float gm = __expf(-fmaxf(fmaf(dt, wdg, bdg), 0.f));
    pool[O_XH + lane * 8 + wave] = mt * xt + (1.f - mt) * (gm * xl + (1.f - gm) * xmv);
  }
  __syncthreads();

  for (int t = 0; t < T_STEPS; ++t) {
    // ===== P1: fused routing + GRU. 12 waves = (rim r, row-quad q).
    // Each wave recomputes its own K0/Q quads (dup across rims -- loads are cheap,
    // LDS exchange is not: R7/R8 evidence), derives p0 in-wave, folds p0 post-GEMM.
    if (wave < 12) {
      const int r = wave >> 1, q = wave & 1;
      // routing sub-GEMM: K0 = xh@Wk, Qr = h_r@Wq_r (quads; bit-same math as R8 G0)
      float4 k0a = {0, 0, 0, 0}, qa = {0, 0, 0, 0};
      {
        const float* Wqr = Wq + r * 4096;
        const float* xh = pool + O_XH;
        const float* hT = pool + O_HT + r * 512;
#pragma unroll 8
        for (int k = 0; k < 64; ++k) {
          float wk = Wk[k * 64 + lane];
          float wq = Wqr[k * 64 + lane];
          float4 sx = *(const float4*)&xh[k * 8 + q * 4];
          float4 sh = *(const float4*)&hT[k * 8 + q * 4];
          fma4(k0a, sx, wk);
          fma4(qa, sh, wq);
        }
      }
      float dd0 = qa.x * k0a.x, dd1 = qa.y * k0a.y, dd2 = qa.z * k0a.z, dd3 = qa.w * k0a.w;
#pragma unroll
      for (int d = 1; d < 64; d <<= 1) {
        dd0 += __shfl_xor(dd0, d, 64); dd1 += __shfl_xor(dd1, d, 64);
        dd2 += __shfl_xor(dd2, d, 64); dd3 += __shfl_xor(dd3, d, 64);
      }
      float lg0 = dd0 * 0.125f, lg1 = dd1 * 0.125f, lg2 = dd2 * 0.125f, lg3 = dd3 * 0.125f;
      if (lane == 0) {   // publish logits for C2's act ranking
        pool[O_LG + (q * 4 + 0) * 6 + r] = lg0;
        pool[O_LG + (q * 4 + 1) * 6 + r] = lg1;
        pool[O_LG + (q * 4 + 2) * 6 + r] = lg2;
        pool[O_LG + (q * 4 + 3) * 6 + r] = lg3;
      }
      float p00 = sigmoidf_(lg0), p01 = sigmoidf_(lg1);
      float p02 = sigmoidf_(lg2), p03 = sigmoidf_(lg3);
      // big GEMM (R4-style, registers resident, GRU inline; p0 folded after)
      const float* Wc = Wcomb + r * 12288;   // [64][192]
      const float* Wh = Whh + r * 12288;     // [64][192]
      float4 ua = {0,0,0,0}, uz = {0,0,0,0}, un = {0,0,0,0};
      float4 ga = {0,0,0,0}, gz = {0,0,0,0}, gn = {0,0,0,0};
#pragma unroll 4
      for (int k = 0; k < 64; ++k) {
        float w0 = Wc[k * 192 + lane], w1 = Wc[k * 192 + 64 + lane],
              w2 = Wc[k * 192 + 128 + lane];
        float v0 = Wh[k * 192 + lane], v1 = Wh[k * 192 + 64 + lane],
              v2 = Wh[k * 192 + 128 + lane];
        float4 xv = *(const float4*)&pool[O_XH + k * 8 + q * 4];
        float4 hv = *(const float4*)&pool[O_HT + r * 512 + k * 8 + q * 4];
        fma4(ua, xv, w0); fma4(uz, xv, w1); fma4(un, xv, w2);
        fma4(ga, hv, v0); fma4(gz, hv, v1); fma4(gn, hv, v2);
      }
      float4 hold = *(const float4*)&pool[O_HT + (r * 64 + lane) * 8 + q * 4];
      auto gru1 = [&](float p0v, float u0, float u1, float u2, float g0, float g1,
                      float g2, float holdv) -> float {
        float rg = sigmoidf_(fmaf(p0v, u0, g0) + bR);
        float zg = sigmoidf_(fmaf(p0v, u1, g1) + bZ);
        float ng = tanhf_(fmaf(p0v, u2, bin) + rg * (g2 + bhn));
        return (1.f - zg) * ng + zg * holdv;
      };
      float4 hn;
      hn.x = gru1(p00, ua.x, uz.x, un.x, ga.x, gz.x, gn.x, hold.x);
      hn.y = gru1(p01, ua.y, uz.y, un.y, ga.y, gz.y, gn.y, hold.y);
      hn.z = gru1(p02, ua.z, uz.z, un.z, ga.z, gz.z, gn.z, hold.z);
      hn.w = gru1(p03, ua.w, uz.w, un.w, ga.w, gz.w, gn.w, hold.w);
      *(float4*)&pool[O_HNT + (r * 64 + lane) * 8 + q * 4] = hn;
    }
    __syncthreads();
    // ===== P2: C1 — 30 no-dup units (qc 12, kc 12, vc 6), balanced on 16 waves
    for (int u = wave; u < 30; u += 16) {
      const float* W; float* dst; int wstride, r;
      if (u < 12) {
        r = u >> 1; const int ch = u & 1;
        W = Wqc + r * 8192 + ch * 64; wstride = 128;
        dst = pool + O_QC + r * 8 * 128 + ch * 64;
      } else if (u < 24) {
        const int v = u - 12; r = v >> 1; const int ch = v & 1;
        W = Wkc + r * 8192 + ch * 64; wstride = 128;
        dst = pool + O_KC + r * 8 * 128 + ch * 64;
      } else {
        r = u - 24;
        W = Wvc + r * 4096; wstride = 64;
        dst = pool + O_VC + r * 8 * 64;
      }
      const float* hn = pool + O_HNT + r * 512;
      float4 aL = {0, 0, 0, 0}, aH = {0, 0, 0, 0};
#pragma unroll 8
      for (int k = 0; k < 64; ++k) {
        float w = W[(size_t)k * wstride + lane];
        float4 h0 = *(const float4*)&hn[k * 8];
        float4 h1 = *(const float4*)&hn[k * 8 + 4];
        fma4(aL, h0, w); fma4(aH, h1, w);
      }
      const int ds = (u < 24) ? 128 : 64;
      dst[0 * ds + lane] = aL.x; dst[1 * ds + lane] = aL.y;
      dst[2 * ds + lane] = aL.z; dst[3 * ds + lane] = aL.w;
      dst[4 * ds + lane] = aH.x; dst[5 * ds + lane] = aH.y;
      dst[6 * ds + lane] = aH.z; dst[7 * ds + lane] = aH.w;
    }
    __syncthreads();
    // ===== P3: C2 (act from published logits) + X(t+1)
    {
      float nx = 0.f, nm = 0.f, nd = 0.f, nxl = 0.f;
      if (wave < 8) {   // issue next-step input loads early; latency hides under C2
        const int tn = (t + 1 < T_STEPS) ? (t + 1) : (T_STEPS - 1);
        size_t off = ((size_t)(b0 + wave) * T_STEPS + tn) * 64 + lane;
        nx = x[off]; nm = maskp[off]; nd = delta[off]; nxl = xlast[off];
      }
      const int row = wave >> 1;
      const int half = wave & 1;
      float lg[6];
#pragma unroll
      for (int r2 = 0; r2 < 6; ++r2) lg[r2] = pool[O_LG + row * 6 + r2];
      float kcA[6], kcB[6], vcv[6];
#pragma unroll
      for (int s = 0; s < 6; ++s) {
        kcA[s] = pool[O_KC + (s * 8 + row) * 128 + lane];
        kcB[s] = pool[O_KC + (s * 8 + row) * 128 + 64 + lane];
        vcv[s] = pool[O_VC + (s * 8 + row) * 64 + lane];
      }
      const int cOut = lane >> 4;
      const int srcLane = (cOut & 1) << 5;
      const float inv_sq = 0.17677669529663687f;  // 1/sqrt(QC)
#pragma unroll
      for (int jr = 0; jr < 3; ++jr) {
        const int rr = half * 3 + jr;
        // stable top-4 on logits (== top_k(-null_prob)): rank via exact compares
        int rank = 0;
#pragma unroll
        for (int r2 = 0; r2 < 6; ++r2)
          rank += (lg[r2] > lg[rr]) || (lg[r2] == lg[rr] && r2 < rr);
        const bool active = (rank < 4);
        float qA = pool[O_QC + (rr * 8 + row) * 128 + lane];
        float qB = pool[O_QC + (rr * 8 + row) * 128 + 64 + lane];
        float sL[6], sH[6];
#pragma unroll
        for (int s = 0; s < 6; ++s) {
          float p = qA * kcA[s];
          p += __shfl_xor(p, 1, 64); p += __shfl_xor(p, 2, 64); p += __shfl_xor(p, 4, 64);
          p += __shfl_xor(p, 8, 64); p += __shfl_xor(p, 16, 64);
          sL[s] = p * inv_sq;   // heads 0/1 (lane<32 / lane>=32)
          float q2 = qB * kcB[s];
          q2 += __shfl_xor(q2, 1, 64); q2 += __shfl_xor(q2, 2, 64);
          q2 += __shfl_xor(q2, 4, 64); q2 += __shfl_xor(q2, 8, 64);
          q2 += __shfl_xor(q2, 16, 64);
          sH[s] = q2 * inv_sq;  // heads 2/3
        }
        float mL = sL[0], mH = sH[0];
#pragma unroll
        for (int s = 1; s < 6; ++s) { mL = fmaxf(mL, sL[s]); mH = fmaxf(mH, sH[s]); }
        float sumL = 0.f, sumH = 0.f;
#pragma unroll
        for (int s = 0; s < 6; ++s) {
          sL[s] = __expf(sL[s] - mL); sumL += sL[s];
          sH[s] = __expf(sH[s] - mH); sumH += sH[s];
        }
        float rLn = 1.f / sumL, rHn = 1.f / sumH;
        float comm = 0.f;
#pragma unroll
        for (int s = 0; s < 6; ++s) {
          float tL = __shfl(sL[s] * rLn, srcLane, 64);
          float tH = __shfl(sH[s] * rHn, srcLane, 64);
          float cp = (cOut < 2) ? tL : tH;
          comm = fmaf(cp, vcv[s], comm);
        }
        float hnv = pool[O_HNT + (rr * 64 + lane) * 8 + row];
        float hov = pool[O_HT + (rr * 64 + lane) * 8 + row];
        pool[O_HT + (rr * 64 + lane) * 8 + row] = active ? (hnv + comm) : hov;
      }
      // GRU-D imputation for t+1 (XH unread until next P1)
      if (wave < 8) {
        float gm = __expf(-fmaxf(fmaf(nd, wdg, bdg), 0.f));
        pool[O_XH + lane * 8 + wave] = nm * nx + (1.f - nm) * (gm * nxl + (1.f - gm) * xmv);
      }
    }
    __syncthreads();
  }  // t

  // ---------------- final MLP head (waves 0..7, row = wave)
  if (wave < 8) {
    const int b = b0 + wave;
    float acc[10];
#pragma unroll
    for (int o = 0; o < 10; ++o) acc[o] = 0.f;
#pragma unroll
    for (int ii = 0; ii < 6; ++ii) {
      float f = pool[O_HT + (ii * 64 + lane) * 8 + wave];
      const float* w = W1 + (ii * 64 + lane) * 10;
#pragma unroll
      for (int o = 0; o < 10; ++o) acc[o] = fmaf(f, w[o], acc[o]);
    }
    if (lane < 16) {
      float f = statics[(size_t)b * 16 + lane];
      const float* w = W1 + (384 + lane) * 10;
#pragma unroll
      for (int o = 0; o < 10; ++o) acc[o] = fmaf(f, w[o], acc[o]);
    }
#pragma unroll
    for (int o = 0; o < 10; ++o) {
#pragma unroll
      for (int d = 1; d < 64; d <<= 1) acc[o] += __shfl_xor(acc[o], d, 64);
    }
    if (lane == 0) {
      float o0 = b2[0], o1 = b2[1];
#pragma unroll
      for (int o = 0; o < 10; ++o) {
        float a = fmaxf(acc[o] + b1[o], 0.f);
        o0 = fmaf(a, W2[o * 2 + 0], o0);
        o1 = fmaf(a, W2[o * 2 + 1], o1);
      }
      out[(size_t)b * 2 + 0] = o0;
      out[(size_t)b * 2 + 1] = o1;
    }
  }
}

extern "C" void kernel_launch(void* const* d_in, const int* in_sizes, int n_in,
                              void* d_out, int out_size, void* d_ws, size_t ws_size,
                              hipStream_t stream) {
  const float* x       = (const float*)d_in[0];
  const float* statics = (const float*)d_in[1];
  const float* maskp   = (const float*)d_in[2];
  const float* delta   = (const float*)d_in[3];
  const float* xlast   = (const float*)d_in[4];
  const float* xmean   = (const float*)d_in[5];
  const float* wdg     = (const float*)d_in[6];
  const float* bdg     = (const float*)d_in[7];
  const float* Wk      = (const float*)d_in[8];
  const float* Wv      = (const float*)d_in[9];
  const float* Wq      = (const float*)d_in[10];
  const float* Wih     = (const float*)d_in[11];
  const float* Whh     = (const float*)d_in[12];
  const float* bih     = (const float*)d_in[13];
  const float* bhh     = (const float*)d_in[14];
  const float* Wqc     = (const float*)d_in[15];
  const float* Wkc     = (const float*)d_in[16];
  const float* Wvc     = (const float*)d_in[17];
  const float* W1      = (const float*)d_in[18];
  const float* b1      = (const float*)d_in[19];
  const float* W2      = (const float*)d_in[20];
  const float* b2      = (const float*)d_in[21];
  float* Wcomb = (float*)d_ws;  // 6*64*192 floats = 294912 B

  wcomb_kernel<<<384, 192, 0, stream>>>(Wv, Wih, Wcomb);
  rims_kernel<<<256, 1024, 0, stream>>>(x, statics, maskp, delta, xlast, xmean,
                                        wdg, bdg, Wk, Wq, Whh, bih, bhh,
                                        Wqc, Wkc, Wvc, W1, b1, W2, b2,
                                        Wcomb, (float*)d_out);
}